// Round 14
// baseline (364.607 us; speedup 1.0000x reference)
//
#include <hip/hip_runtime.h>
#include <math.h>

// Problem: scores = q[2048x768] @ p[16384x768]^T (fp32 in), per-query
// rank-of-target + log-softmax CE + Gaussian rank weight -> mean (scalar).
// R15: MX-scaled MFMA. R14 post-mortem: sched_barrier interleave flat
// (58.9 us, MfmaUtil 33) -> per-iter convoy overhead (~3.4k cyc) dominates
// over the ~2.5k cyc of 16x16 MFMA work. Pre-declared branch: switch to
// mfma_scale_f32_32x32x64_f8f6f4 with UNIT scales (e8m0 127 = x1.0 ->
// numerically plain fp8 matmul, K-sum reordered):
//  - 2x FLOP rate (4686 vs 2047 TF), 8x fewer MFMA instrs (4/wave/K-tile).
//  - BK=128, KITERS=6, DOUBLE buffer (2 x 16 units x 4KB = 128KB LDS):
//    halves barrier count -> convoy overhead amortizes 2x.
//  - LDS unit [kc(8)][row(32)][16B] = 4KB; one unit staged per wave
//    (4 x global_load_lds: lane l -> row l&31, kc 2v+(l>>5)). Frag read:
//    2 x ds_read_b128 per operand (kc = h*4+(l>>5)*2 +{0,1}, byte
//    kc*512+(l&31)*16) -> conflict-free (same 16-lane bank proof as R13).
//  - A/B frag: lane l holds row l&31, k = (l>>5)*32+[0,32) (analogy of
//    verified 16x16x32 layout). C/D 32x32: col=lane&31,
//    row=(reg&3)+8*(reg>>2)+4*(lane>>5) (m74/m101, shape-determined).
//  - Epilogue reworked for 32x32 tiles; chunk map + pm/pl/pc + finalize
//    UNCHANGED (chunk = nb*4+wn still owns 64 cols).
// Pipeline per iter: [vmcnt(0): stage(kt) done - issued a full iter ago,
// zero-cost] [s_barrier] [STAGE(kt+1, cb^1): buf last read iter kt-1,
// safe] [COMPUTE cb: 2 K-halves x {8 ds_read_b128, 4 MFMA}].
// Predict: gemm ~35-42 us, total ~125-135, absmax ~0.5.
// (Resubmission of R15 with the FRAG/CB macro-parameter compile fix:
//  FRAG now takes the buffer index explicitly.)

#define BQ 2048
#define DD 768
#define NPASS 8
#define PP 16384
#define BM 256
#define BN 256
#define BK 128
#define KITERS 6           // 768/128
#define NBLK 64            // PP/BN
#define MBLK 8             // BQ/BM
#define NCHUNKS 256        // NBLK * 4 n-waves

#define ALPHA_C 2.6f
#define INV_2SIG2 (1.0f/6.48f)   // 1/(2*1.8^2)

typedef __attribute__((ext_vector_type(16))) float floatx16; // 32x32 C/D
typedef __attribute__((ext_vector_type(4))) int intx4;       // ds_read_b128
typedef __attribute__((ext_vector_type(8))) int intx8;       // MFMA A/B

// ---------------------------------------------------------------------------
// Kernel 1 (fused): cast q,p -> fp8 e4m3  +  s_t exact-fp32 dots  +  out=0.
// (unchanged)
// ---------------------------------------------------------------------------
#define NQ8   196608     // 2048*768/8
#define NTOT8 1769472    // (2048+16384)*768/8
#define NCB   6912       // NTOT8/256
__global__ __launch_bounds__(256) void prep_kernel(const float* __restrict__ qf,
                                                   const float* __restrict__ pf,
                                                   uint2* __restrict__ qb,
                                                   uint2* __restrict__ pb,
                                                   float* __restrict__ st,
                                                   float* __restrict__ out) {
  const int b = blockIdx.x;
  if (b == 0 && threadIdx.x == 0) *out = 0.f;
  if (b < NCB) {
    const int i = b * 256 + threadIdx.x;        // float8 index
    const float4* src; uint2* dst;
    if (i < NQ8) { src = (const float4*)qf + 2 * (size_t)i; dst = qb + i; }
    else { const size_t j = (size_t)i - NQ8; src = (const float4*)pf + 2 * j; dst = pb + j; }
    const float4 a = src[0], c = src[1];
    unsigned lo = __builtin_amdgcn_cvt_pk_fp8_f32(a.x, a.y, 0, 0);
    lo = __builtin_amdgcn_cvt_pk_fp8_f32(a.z, a.w, lo, 1);
    unsigned hi = __builtin_amdgcn_cvt_pk_fp8_f32(c.x, c.y, 0, 0);
    hi = __builtin_amdgcn_cvt_pk_fp8_f32(c.z, c.w, hi, 1);
    uint2 w; w.x = lo; w.y = hi;
    *dst = w;
  } else {
    const int wv = threadIdx.x >> 6, lane = threadIdx.x & 63;
    const int qi = (b - NCB) * 4 + wv;
    const float4* q4 = (const float4*)(qf + (size_t)qi * DD);
    const float4* p4 = (const float4*)(pf + (size_t)qi * NPASS * DD);
    float acc = 0.f;
#pragma unroll
    for (int u = 0; u < 3; ++u) {   // 192 float4 per row = 64 lanes * 3
      float4 a = q4[lane + 64 * u];
      float4 c = p4[lane + 64 * u];
      acc = fmaf(a.x, c.x, acc);
      acc = fmaf(a.y, c.y, acc);
      acc = fmaf(a.z, c.z, acc);
      acc = fmaf(a.w, c.w, acc);
    }
#pragma unroll
    for (int off = 32; off >= 1; off >>= 1) acc += __shfl_xor(acc, off);
    if (lane == 0) st[qi] = acc;
  }
}

// ---------------------------------------------------------------------------
// Kernel 2: MX-scaled fp8 GEMM 256x256, BK=128, double-buffered.
// 16 waves (4m x 4n), each wave 2x2 tiles of 32x32 (64x64 out).
// Unit u (4KB) = 32 rows x 128 k-bytes in [kc][row][16B] layout; units
// 0-7 = A (rows u*32), 8-15 = B (cols (u-8)*32); wave wv stages unit wv.
// ---------------------------------------------------------------------------
__global__ __launch_bounds__(1024) void gemm_kernel(const unsigned char* __restrict__ qb,
                                                    const unsigned char* __restrict__ pb,
                                                    const float* __restrict__ st,
                                                    float* __restrict__ pm,
                                                    float* __restrict__ pl,
                                                    float* __restrict__ pc) {
  __shared__ unsigned char Ts[2][16 * 4096];   // 128 KB
  __shared__ float st_lds[BM];

  const int t = threadIdx.x;
  const int lane = t & 63;
  const int wv = t >> 6;            // 0..15
  const int wm = wv >> 2, wn = wv & 3;
  const int bid = blockIdx.x;       // 0..511
  const int xcd = bid & 7;          // round-robin XCD assignment
  const int nb = xcd * 8 + ((bid >> 3) & 7);   // XCD-private pb slice (1.5 MB)
  const int mb = bid >> 6;          // 0..7
  const int qbase = mb * BM;
  const int n0 = nb * BN;
  const int lm32 = lane & 31;
  const int lhi = lane >> 5;

  if (t < BM) st_lds[t] = st[qbase + t];

  floatx16 acc[2][2];
#pragma unroll
  for (int i = 0; i < 2; ++i)
#pragma unroll
    for (int j = 0; j < 2; ++j)
#pragma unroll
      for (int r = 0; r < 16; ++r) acc[i][j][r] = 0.f;

  // staging role: wave wv owns unit wv (A rows / B rows = p cols)
  const int srow = (wv < 8) ? (qbase + wv * 32) : (n0 + (wv - 8) * 32);
  const unsigned char* const sbase =
      ((wv < 8) ? qb : pb) + (size_t)(srow + lm32) * DD;

  // stage(kt, buf): 4 x global_load_lds of 1KB; LDS byte v*1024 + lane*16
  // decodes to kc = 2v+(lane>>5), row = lane&31 in the [kc][row][16B] unit.
#define STAGE(KT, BUF)                                                          \
  {                                                                             \
    _Pragma("unroll")                                                           \
    for (int v = 0; v < 4; ++v) {                                               \
      __builtin_amdgcn_global_load_lds(                                         \
          (const __attribute__((address_space(1))) void*)(sbase + (KT) * BK + (2 * v + lhi) * 16), \
          (__attribute__((address_space(3))) void*)(&Ts[BUF][wv * 4096 + v * 1024] + lane * 16), \
          16, 0, 0);                                                            \
    }                                                                           \
  }

  // frag: lane l needs row l&31, k = h*64 + (l>>5)*32 + [0,32) ->
  // kc = h*4 + (l>>5)*2 + {0,1}; two b128 reads concatenated to v8i32.
#define FRAG(dst, CBUF, UNIT, H)                                                \
  {                                                                             \
    const unsigned char* ub = &Ts[CBUF][(UNIT) * 4096] +                        \
                              ((H) * 4 + lhi * 2) * 512 + lm32 * 16;            \
    intx4 lo = *(const intx4*)ub;                                               \
    intx4 hi = *(const intx4*)(ub + 512);                                       \
    dst = __builtin_shufflevector(lo, hi, 0, 1, 2, 3, 4, 5, 6, 7);              \
  }

  // per K-half: 8 ds_read_b128 + 4 scaled MFMAs (scale=127 -> x1.0 = plain fp8)
#define COMPUTE(CBUF)                                                           \
  _Pragma("unroll")                                                             \
  for (int h = 0; h < 2; ++h) {                                                 \
    intx8 af[2], bf[2];                                                         \
    FRAG(af[0], CBUF, wm * 2 + 0, h)                                            \
    FRAG(af[1], CBUF, wm * 2 + 1, h)                                            \
    FRAG(bf[0], CBUF, 8 + wn * 2 + 0, h)                                        \
    FRAG(bf[1], CBUF, 8 + wn * 2 + 1, h)                                        \
    __builtin_amdgcn_s_setprio(1);                                              \
    acc[0][0] = __builtin_amdgcn_mfma_scale_f32_32x32x64_f8f6f4(af[0], bf[0], acc[0][0], 0, 0, 0, 127, 0, 127); \
    acc[0][1] = __builtin_amdgcn_mfma_scale_f32_32x32x64_f8f6f4(af[0], bf[1], acc[0][1], 0, 0, 0, 127, 0, 127); \
    acc[1][0] = __builtin_amdgcn_mfma_scale_f32_32x32x64_f8f6f4(af[1], bf[0], acc[1][0], 0, 0, 0, 127, 0, 127); \
    acc[1][1] = __builtin_amdgcn_mfma_scale_f32_32x32x64_f8f6f4(af[1], bf[1], acc[1][1], 0, 0, 0, 127, 0, 127); \
    __builtin_amdgcn_s_setprio(0);                                              \
  }

  STAGE(0, 0)
  for (int kt = 0; kt < KITERS; ++kt) {
    const int cb = kt & 1;
    // stage(kt) was issued a full iteration ago -> vmcnt(0) is ~free here
    asm volatile("s_waitcnt vmcnt(0)" ::: "memory");
    __builtin_amdgcn_s_barrier();          // all units of buf cb complete;
    __builtin_amdgcn_sched_barrier(0);     // all waves past iter kt-1 reads
    if (kt < KITERS - 1) STAGE(kt + 1, cb ^ 1)   // flies under compute below
    if (cb == 0) { COMPUTE(0) } else { COMPUTE(1) }
  }

  // ---- fused epilogue: per-row max / sumexp / count over 64 cols ----
  // C/D 32x32: col = lane&31, row = (r&3)+8*(r>>2)+4*(lane>>5). Half-wave
  // (32 lanes) holds one row's 32 cols of tile j -> shfl_xor offsets 1..16
  // reduce within each half independently. Chunk-major partials unchanged.
  const int chunk = nb * 4 + wn;
  float* const pmc = pm + (size_t)chunk * BQ;
  float* const plc = pl + (size_t)chunk * BQ;
  float* const pcc = pc + (size_t)chunk * BQ;
  const int cgbase = n0 + wn * 64 + lm32;
#pragma unroll
  for (int i = 0; i < 2; ++i) {
#pragma unroll
    for (int r = 0; r < 16; ++r) {
      const int rl = wm * 64 + i * 32 + (r & 3) + 8 * (r >> 2) + 4 * lhi;
      const float s0 = acc[i][0][r], s1 = acc[i][1][r];
      float mx = fmaxf(s0, s1);
#pragma unroll
      for (int off = 1; off <= 16; off <<= 1) mx = fmaxf(mx, __shfl_xor(mx, off));
      const float stv = st_lds[rl];
      const int qg = qbase + rl;
      const int tcol = qg * NPASS;
      float sum = __expf(s0 - mx) + __expf(s1 - mx);
      float c = 0.f;
      if (s0 > stv && cgbase != tcol) c += 1.f;
      if (s1 > stv && cgbase + 32 != tcol) c += 1.f;
#pragma unroll
      for (int off = 1; off <= 16; off <<= 1) {
        sum += __shfl_xor(sum, off);
        c += __shfl_xor(c, off);
      }
      if (lm32 == 0) {
        pmc[qg] = mx; plc[qg] = sum; pcc[qg] = c;
      }
    }
  }
}

// ---------------------------------------------------------------------------
// Kernel 3: merge 256 chunks/query (chunk-major partials), weighted CE, mean.
// (unchanged)
// ---------------------------------------------------------------------------
__global__ __launch_bounds__(256) void finalize_kernel(const float* __restrict__ st,
                                                       const float* __restrict__ pm,
                                                       const float* __restrict__ pl,
                                                       const float* __restrict__ pc,
                                                       float* __restrict__ out) {
  const int wv = threadIdx.x >> 6, lane = threadIdx.x & 63;
  const int q = blockIdx.x * 64 + lane;
  const int c0 = wv * 64;
  float m = -1e30f, l = 0.f, c = 0.f;
#pragma unroll 4
  for (int ch = 0; ch < 64; ++ch) {
    const size_t idx = (size_t)(c0 + ch) * BQ + q;
    const float mv = pm[idx], lv = pl[idx], cv = pc[idx];
    const float nm = fmaxf(m, mv);
    l = l * __expf(m - nm) + lv * __expf(mv - nm);
    m = nm; c += cv;
  }
  __shared__ float sm[4][64], sl[4][64], sc[4][64];
  sm[wv][lane] = m; sl[wv][lane] = l; sc[wv][lane] = c;
  __syncthreads();
  if (wv == 0) {
    float M = sm[0][lane], L = sl[0][lane], C = sc[0][lane];
#pragma unroll
    for (int w = 1; w < 4; ++w) {
      const float mv = sm[w][lane];
      const float nm = fmaxf(M, mv);
      L = L * __expf(M - nm) + sl[w][lane] * __expf(mv - nm);
      M = nm; C += sc[w][lane];
    }
    const float raw = logf(L) + M - st[q];     // -log_softmax[target]
    const float dr = C - 1.0f;                 // rank - OPTIMAL_RANK
    const float w = 1.0f + ALPHA_C * __expf(-(dr * dr) * INV_2SIG2);
    float loss = raw * w * (1.0f / (float)BQ);
#pragma unroll
    for (int off = 32; off >= 1; off >>= 1) loss += __shfl_xor(loss, off);
    if (lane == 0) atomicAdd(out, loss);
  }
}

// ---------------------------------------------------------------------------
extern "C" void kernel_launch(void* const* d_in, const int* in_sizes, int n_in,
                              void* d_out, int out_size, void* d_ws, size_t ws_size,
                              hipStream_t stream) {
  const float* q = (const float*)d_in[0];
  const float* p = (const float*)d_in[1];
  char* ws = (char*)d_ws;
  unsigned char* qb = (unsigned char*)ws;                  // 1,572,864 B
  unsigned char* pb = (unsigned char*)(ws + 1572864);      // 12,582,912 B
  float* st = (float*)(ws + 14155776);                     // 8 KB
  float* pm = (float*)(ws + 14163968);                     // 2 MB
  float* pl = (float*)(ws + 16261120);                     // 2 MB
  float* pc = (float*)(ws + 18358272);                     // 2 MB (end ~20.5 MB)
  float* out = (float*)d_out;

  prep_kernel<<<NCB + BQ / 4, 256, 0, stream>>>(q, p, (uint2*)qb, (uint2*)pb, st, out);
  gemm_kernel<<<NBLK * MBLK, 1024, 0, stream>>>(qb, pb, st, pm, pl, pc);
  finalize_kernel<<<BQ / 64, 256, 0, stream>>>(st, pm, pl, pc, out);
}

// Round 15
// 153.665 us; speedup vs baseline: 2.3727x; 2.3727x over previous
//
#include <hip/hip_runtime.h>
#include <math.h>

// Problem: scores = q[2048x768] @ p[16384x768]^T (fp32 in), per-query
// rank-of-target + log-softmax CE + Gaussian rank weight -> mean (scalar).
// R16: 2-resident-blocks geometry. R15 post-mortem: MX-scaled MFMA was
// CORRECT (absmax 0.5) but spilled acc to scratch (WRITE 522 MB, gemm
// 264 us) -> reverted. R14's residual: 5k of 5.95k cyc/iter is wait with
// ONE block/CU (LDS 99KB, 124 regs x 16 waves = full CU) -> nothing covers
// the convoy. R11's 8-wave attempt failed at 72+64=136 regs/wave (15
// waves/CU -> still 1 block, occupancy 22.5%) AND used vmcnt(0) drains.
// R16 = proven R12-R14 pipeline (triple buffer, counted vmcnt, R13
// conflict-free b128 K-permuted reads, R14 3-phase interleave) at
// 128x256/512-thr/8-wave with __launch_bounds__(512,4) pinning <=128
// regs/wave: LDS 3x24+0.5 = 72.5 KB, 16 waves/CU -> TWO resident blocks
// whose convoys interleave (m114). Same fp8 values + K-order -> absmax 0.5.
// Predict: Occupancy 37->~50, gemm 58.9->42-50 us, MfmaUtil 33->42-50,
// FETCH ~12.4 MB, WRITE 6.1 MB, conflicts 0, total ~135-145.

#define BQ 2048
#define DD 768
#define NPASS 8
#define PP 16384
#define BM 128
#define BN 256
#define BK 64
#define KITERS 12          // 768/64
#define NBLK 64            // PP/BN
#define MBLK 16            // BQ/BM
#define NCHUNKS 256        // NBLK * 4 n-waves

#define ALPHA_C 2.6f
#define INV_2SIG2 (1.0f/6.48f)   // 1/(2*1.8^2)

typedef __attribute__((ext_vector_type(4))) float floatx4;  // MFMA C/D
typedef __attribute__((ext_vector_type(2))) long longx2;    // ds_read_b128

// ---------------------------------------------------------------------------
// Kernel 1 (fused): cast q,p -> fp8 e4m3  +  s_t exact-fp32 dots  +  out=0.
// (unchanged)
// ---------------------------------------------------------------------------
#define NQ8   196608     // 2048*768/8
#define NTOT8 1769472    // (2048+16384)*768/8
#define NCB   6912       // NTOT8/256
__global__ __launch_bounds__(256) void prep_kernel(const float* __restrict__ qf,
                                                   const float* __restrict__ pf,
                                                   uint2* __restrict__ qb,
                                                   uint2* __restrict__ pb,
                                                   float* __restrict__ st,
                                                   float* __restrict__ out) {
  const int b = blockIdx.x;
  if (b == 0 && threadIdx.x == 0) *out = 0.f;
  if (b < NCB) {
    const int i = b * 256 + threadIdx.x;        // float8 index
    const float4* src; uint2* dst;
    if (i < NQ8) { src = (const float4*)qf + 2 * (size_t)i; dst = qb + i; }
    else { const size_t j = (size_t)i - NQ8; src = (const float4*)pf + 2 * j; dst = pb + j; }
    const float4 a = src[0], c = src[1];
    unsigned lo = __builtin_amdgcn_cvt_pk_fp8_f32(a.x, a.y, 0, 0);
    lo = __builtin_amdgcn_cvt_pk_fp8_f32(a.z, a.w, lo, 1);
    unsigned hi = __builtin_amdgcn_cvt_pk_fp8_f32(c.x, c.y, 0, 0);
    hi = __builtin_amdgcn_cvt_pk_fp8_f32(c.z, c.w, hi, 1);
    uint2 w; w.x = lo; w.y = hi;
    *dst = w;
  } else {
    const int wv = threadIdx.x >> 6, lane = threadIdx.x & 63;
    const int qi = (b - NCB) * 4 + wv;
    const float4* q4 = (const float4*)(qf + (size_t)qi * DD);
    const float4* p4 = (const float4*)(pf + (size_t)qi * NPASS * DD);
    float acc = 0.f;
#pragma unroll
    for (int u = 0; u < 3; ++u) {   // 192 float4 per row = 64 lanes * 3
      float4 a = q4[lane + 64 * u];
      float4 c = p4[lane + 64 * u];
      acc = fmaf(a.x, c.x, acc);
      acc = fmaf(a.y, c.y, acc);
      acc = fmaf(a.z, c.z, acc);
      acc = fmaf(a.w, c.w, acc);
    }
#pragma unroll
    for (int off = 32; off >= 1; off >>= 1) acc += __shfl_xor(acc, off);
    if (lane == 0) st[qi] = acc;
  }
}

// ---------------------------------------------------------------------------
// Kernel 2: fp8 MFMA GEMM 128x256, BK=64, TRIPLE-buffered global_load_lds,
// counted vmcnt, 8 waves (2m x 4n), wave = 64x64 out (4x4 of 16x16x32).
// LDS/buf: A 8 units (rows wv*16), B 16 units (rows wv*32, 2 units/wave) =
// 24 KB; 3 buffers = 72 KB; 2 blocks/CU resident (<=128 regs/wave via
// launch_bounds). Unit = 16 rows x 64 k-bytes, [kchunk 16B][row][16B]:
// staged wave-uniform base + lane*16. Frag read (R13, conflict-free):
// ONE ds_read_b128/unit/lane at intra16 = lq*256+lm*16 -> row lm, global
// k = lq*16..+16; MFMA ks=0 <- bytes [0,8), ks=1 <- [8,16) (K-bijection
// same for A and B). C/D: col=lane&15, row=(lane>>4)*4+reg.
// Pipeline per iter t: [vmcnt(3): own stage-t's 3 loads done, stage-t+1's
// 3 still in flight] [s_barrier] [STAGE(t+2) into buf (t+2)%3 - last read
// at t-1, provably free] [R14 3-phase interleaved compute of buf t%3].
// ---------------------------------------------------------------------------
__global__ __launch_bounds__(512, 4) void gemm_kernel(const unsigned char* __restrict__ qb,
                                                      const unsigned char* __restrict__ pb,
                                                      const float* __restrict__ st,
                                                      float* __restrict__ pm,
                                                      float* __restrict__ pl,
                                                      float* __restrict__ pc) {
  __shared__ unsigned char As[3][8 * 1024];    // 24 KB
  __shared__ unsigned char Bs[3][16 * 1024];   // 48 KB
  __shared__ float st_lds[BM];

  const int t = threadIdx.x;
  const int lane = t & 63;
  const int wv = t >> 6;            // 0..7
  const int wm = wv >> 2, wn = wv & 3;
  const int bid = blockIdx.x;       // 0..1023
  const int xcd = bid & 7;          // round-robin XCD assignment
  const int nb = xcd * 8 + ((bid >> 3) & 7);   // XCD-private pb slice (1.5 MB)
  const int mb = bid >> 6;          // 0..15
  const int qbase = mb * BM;
  const int n0 = nb * BN;
  const int lm = lane & 15;
  const int lq = lane >> 4;
  const int lds_lane = lane * 16;

  if (t < BM) st_lds[t] = st[qbase + t];

  floatx4 acc[4][4];
#pragma unroll
  for (int i = 0; i < 4; ++i)
#pragma unroll
    for (int j = 0; j < 4; ++j) acc[i][j] = (floatx4){0.f, 0.f, 0.f, 0.f};

  const size_t arow = (size_t)(qbase + wv * 16 + lm) * DD;
  const size_t brow = (size_t)(n0 + wv * 32 + lm) * DD;
  const int intra16 = lq * 256 + lm * 16;      // one 16-B chunk per lane

  // stage(kt, buf): 3 loads/wave (A unit wv; B units wv*2, wv*2+1), 1 KB each.
#define STAGE(KT, BUF)                                                          \
  {                                                                             \
    const size_t koff = (size_t)(KT) * BK + lq * 16;                            \
    __builtin_amdgcn_global_load_lds(                                           \
        (const __attribute__((address_space(1))) void*)(qb + arow + koff),      \
        (__attribute__((address_space(3))) void*)(&As[BUF][wv * 1024] + lds_lane), \
        16, 0, 0);                                                              \
    _Pragma("unroll")                                                           \
    for (int u = 0; u < 2; ++u) {                                               \
      __builtin_amdgcn_global_load_lds(                                         \
          (const __attribute__((address_space(1))) void*)(pb + brow + (size_t)u * 16 * DD + koff), \
          (__attribute__((address_space(3))) void*)(&Bs[BUF][(wv * 2 + u) * 1024] + lds_lane), \
          16, 0, 0);                                                            \
    }                                                                           \
  }

  // 8 MFMAs for (i-pair II, j-pair JJ): 4 acc tiles x 2 ks, same-acc pair
  // spaced 4 apart (no back-to-back acc dependency).
#define MFMA8(II, JJ)                                                           \
  {                                                                             \
    acc[II][JJ]       = __builtin_amdgcn_mfma_f32_16x16x32_fp8_fp8(a2[II].x,     b2[JJ].x,     acc[II][JJ],       0, 0, 0); \
    acc[II][JJ+1]     = __builtin_amdgcn_mfma_f32_16x16x32_fp8_fp8(a2[II].x,     b2[JJ+1].x,   acc[II][JJ+1],     0, 0, 0); \
    acc[II+1][JJ]     = __builtin_amdgcn_mfma_f32_16x16x32_fp8_fp8(a2[II+1].x,   b2[JJ].x,     acc[II+1][JJ],     0, 0, 0); \
    acc[II+1][JJ+1]   = __builtin_amdgcn_mfma_f32_16x16x32_fp8_fp8(a2[II+1].x,   b2[JJ+1].x,   acc[II+1][JJ+1],   0, 0, 0); \
    acc[II][JJ]       = __builtin_amdgcn_mfma_f32_16x16x32_fp8_fp8(a2[II].y,     b2[JJ].y,     acc[II][JJ],       0, 0, 0); \
    acc[II][JJ+1]     = __builtin_amdgcn_mfma_f32_16x16x32_fp8_fp8(a2[II].y,     b2[JJ+1].y,   acc[II][JJ+1],     0, 0, 0); \
    acc[II+1][JJ]     = __builtin_amdgcn_mfma_f32_16x16x32_fp8_fp8(a2[II+1].y,   b2[JJ].y,     acc[II+1][JJ],     0, 0, 0); \
    acc[II+1][JJ+1]   = __builtin_amdgcn_mfma_f32_16x16x32_fp8_fp8(a2[II+1].y,   b2[JJ+1].y,   acc[II+1][JJ+1],   0, 0, 0); \
  }

  // R14 3-phase interleaved compute (A units wm*4+i of 8; B units wn*4+j of 16)
#define COMPUTE(CB)                                                             \
  {                                                                             \
    longx2 a2[4], b2[4];                                                        \
    a2[0] = *(const longx2*)(&As[CB][(wm * 4 + 0) * 1024] + intra16);           \
    a2[1] = *(const longx2*)(&As[CB][(wm * 4 + 1) * 1024] + intra16);           \
    b2[0] = *(const longx2*)(&Bs[CB][(wn * 4 + 0) * 1024] + intra16);           \
    b2[1] = *(const longx2*)(&Bs[CB][(wn * 4 + 1) * 1024] + intra16);           \
    __builtin_amdgcn_sched_barrier(0);                                          \
    b2[2] = *(const longx2*)(&Bs[CB][(wn * 4 + 2) * 1024] + intra16);           \
    b2[3] = *(const longx2*)(&Bs[CB][(wn * 4 + 3) * 1024] + intra16);           \
    __builtin_amdgcn_sched_barrier(0);                                          \
    __builtin_amdgcn_s_setprio(1);                                              \
    MFMA8(0, 0)                                                                 \
    __builtin_amdgcn_s_setprio(0);                                              \
    __builtin_amdgcn_sched_barrier(0);                                          \
    a2[2] = *(const longx2*)(&As[CB][(wm * 4 + 2) * 1024] + intra16);           \
    a2[3] = *(const longx2*)(&As[CB][(wm * 4 + 3) * 1024] + intra16);           \
    __builtin_amdgcn_sched_barrier(0);                                          \
    __builtin_amdgcn_s_setprio(1);                                              \
    MFMA8(0, 2)                                                                 \
    __builtin_amdgcn_s_setprio(0);                                              \
    __builtin_amdgcn_sched_barrier(0);                                          \
    __builtin_amdgcn_s_setprio(1);                                              \
    MFMA8(2, 0)                                                                 \
    MFMA8(2, 2)                                                                 \
    __builtin_amdgcn_s_setprio(0);                                              \
  }

  STAGE(0, 0)
  STAGE(1, 1)
  int cur = 0;            // buffer holding K-tile kt
  int stg = 2;            // buffer to stage K-tile kt+2 into
  for (int kt = 0; kt < KITERS - 1; ++kt) {
    // own stage-kt's 3 loads done (3 newest = stage kt+1 may stay in flight)
    asm volatile("s_waitcnt vmcnt(3)" ::: "memory");
    __builtin_amdgcn_s_barrier();          // all waves: stage kt complete,
    __builtin_amdgcn_sched_barrier(0);     // and all past iter kt-1 reads
    if (kt < KITERS - 2) STAGE(kt + 2, stg)
    COMPUTE(cur)
    cur = (cur == 2) ? 0 : cur + 1;
    stg = (stg == 2) ? 0 : stg + 1;
  }
  // peeled final iteration: drain the last stage
  asm volatile("s_waitcnt vmcnt(0)" ::: "memory");
  __builtin_amdgcn_s_barrier();
  __builtin_amdgcn_sched_barrier(0);
  COMPUTE(cur)

  // ---- fused epilogue: per-row (query) max / sumexp / count over 64 cols ----
  // Chunk-major partials (proven R11): one 64B line per (wave,i) store group.
  const int chunk = nb * 4 + wn;
  float* const pmc = pm + (size_t)chunk * BQ;
  float* const plc = pl + (size_t)chunk * BQ;
  float* const pcc = pc + (size_t)chunk * BQ;
#pragma unroll
  for (int i = 0; i < 4; ++i) {
#pragma unroll
    for (int r = 0; r < 4; ++r) {
      const int rl = wm * 64 + i * 16 + lq * 4 + r;   // local query row
      float mx = fmaxf(fmaxf(acc[i][0][r], acc[i][1][r]),
                       fmaxf(acc[i][2][r], acc[i][3][r]));
#pragma unroll
      for (int off = 1; off <= 8; off <<= 1) mx = fmaxf(mx, __shfl_xor(mx, off));
      const float stv = st_lds[rl];
      const int qg = qbase + rl;
      const int tcol = qg * NPASS;
      float sum = 0.f, c = 0.f;
#pragma unroll
      for (int j = 0; j < 4; ++j) {
        const float s = acc[i][j][r];
        sum += __expf(s - mx);
        const int cg = n0 + wn * 64 + j * 16 + lm;
        if (s > stv && cg != tcol) c += 1.f;
      }
#pragma unroll
      for (int off = 1; off <= 8; off <<= 1) {
        sum += __shfl_xor(sum, off);
        c += __shfl_xor(c, off);
      }
      if (lm == 0) {
        pmc[qg] = mx; plc[qg] = sum; pcc[qg] = c;
      }
    }
  }
}

// ---------------------------------------------------------------------------
// Kernel 3: merge 256 chunks/query (chunk-major partials), weighted CE, mean.
// (unchanged)
// ---------------------------------------------------------------------------
__global__ __launch_bounds__(256) void finalize_kernel(const float* __restrict__ st,
                                                       const float* __restrict__ pm,
                                                       const float* __restrict__ pl,
                                                       const float* __restrict__ pc,
                                                       float* __restrict__ out) {
  const int wv = threadIdx.x >> 6, lane = threadIdx.x & 63;
  const int q = blockIdx.x * 64 + lane;
  const int c0 = wv * 64;
  float m = -1e30f, l = 0.f, c = 0.f;
#pragma unroll 4
  for (int ch = 0; ch < 64; ++ch) {
    const size_t idx = (size_t)(c0 + ch) * BQ + q;
    const float mv = pm[idx], lv = pl[idx], cv = pc[idx];
    const float nm = fmaxf(m, mv);
    l = l * __expf(m - nm) + lv * __expf(mv - nm);
    m = nm; c += cv;
  }
  __shared__ float sm[4][64], sl[4][64], sc[4][64];
  sm[wv][lane] = m; sl[wv][lane] = l; sc[wv][lane] = c;
  __syncthreads();
  if (wv == 0) {
    float M = sm[0][lane], L = sl[0][lane], C = sc[0][lane];
#pragma unroll
    for (int w = 1; w < 4; ++w) {
      const float mv = sm[w][lane];
      const float nm = fmaxf(M, mv);
      L = L * __expf(M - nm) + sl[w][lane] * __expf(mv - nm);
      M = nm; C += sc[w][lane];
    }
    const float raw = logf(L) + M - st[q];     // -log_softmax[target]
    const float dr = C - 1.0f;                 // rank - OPTIMAL_RANK
    const float w = 1.0f + ALPHA_C * __expf(-(dr * dr) * INV_2SIG2);
    float loss = raw * w * (1.0f / (float)BQ);
#pragma unroll
    for (int off = 32; off >= 1; off >>= 1) loss += __shfl_xor(loss, off);
    if (lane == 0) atomicAdd(out, loss);
  }
}

// ---------------------------------------------------------------------------
extern "C" void kernel_launch(void* const* d_in, const int* in_sizes, int n_in,
                              void* d_out, int out_size, void* d_ws, size_t ws_size,
                              hipStream_t stream) {
  const float* q = (const float*)d_in[0];
  const float* p = (const float*)d_in[1];
  char* ws = (char*)d_ws;
  unsigned char* qb = (unsigned char*)ws;                  // 1,572,864 B
  unsigned char* pb = (unsigned char*)(ws + 1572864);      // 12,582,912 B
  float* st = (float*)(ws + 14155776);                     // 8 KB
  float* pm = (float*)(ws + 14163968);                     // 2 MB
  float* pl = (float*)(ws + 16261120);                     // 2 MB
  float* pc = (float*)(ws + 18358272);                     // 2 MB (end ~20.5 MB)
  float* out = (float*)d_out;

  prep_kernel<<<NCB + BQ / 4, 256, 0, stream>>>(q, p, (uint2*)qb, (uint2*)pb, st, out);
  gemm_kernel<<<NBLK * MBLK, 512, 0, stream>>>(qb, pb, st, pm, pl, pc);
  finalize_kernel<<<BQ / 64, 256, 0, stream>>>(st, pm, pl, pc, out);
}